// Round 4
// baseline (936.354 us; speedup 1.0000x reference)
//
#include <hip/hip_runtime.h>

#pragma clang fp contract(off)

#define CDIM 256
#define N_TOKS 8192
#define N_CODES 8192

// ---------------- ws layout (bytes) ----------------
// 0       pairs   u64[8192*8]   512KB   per (token,split) packed (enc(d),idx)
// 524288  A       f32[8192]     32KB    np-pairwise ||z||^2 per token
// 557056  fidx    u32[8192]     32KB
// 589824  counts  u32[8192]     32KB
// 622592  bsum    f32[8]        32B

__device__ __forceinline__ unsigned enc_f(float f) {
    unsigned u = __float_as_uint(f);
    return (u & 0x80000000u) ? ~u : (u | 0x80000000u);
}

// ---------------- A_n = np.sum(zf*zf, axis=1) with numpy pairwise order ----
__global__ void vq_A_kernel(const float* __restrict__ z, float* __restrict__ A) {
    #pragma clang fp contract(off)
    const int n = blockIdx.x * blockDim.x + threadIdx.x;
    const int b = n >> 10, hw = n & 1023;
    const float* zp = z + (size_t)b * (CDIM * 1024) + hw;
    float halves[2];
    #pragma unroll
    for (int h = 0; h < 2; ++h) {
        const int base = h * 128;
        float r[8];
        #pragma unroll
        for (int j = 0; j < 8; ++j) {
            const float v = zp[(size_t)(base + j) * 1024];
            r[j] = v * v;
        }
        for (int i = 8; i < 128; i += 8) {
            #pragma unroll
            for (int j = 0; j < 8; ++j) {
                const float v = zp[(size_t)(base + i + j) * 1024];
                const float x = v * v;
                r[j] = r[j] + x;
            }
        }
        halves[h] = ((r[0] + r[1]) + (r[2] + r[3])) + ((r[4] + r[5]) + (r[6] + r[7]));
    }
    A[n] = halves[0] + halves[1];
}

// ---------------- main argmin: d_k = fl(A - 2*G_k), np.einsum SSE order ----
// Residue-sequential: lane j (channels == j mod 4) computed start-to-finish in
// one LDS phase of 64 channels -> only 3x32 live accumulators (no spills).
// G = (l0+l1)+(l2+l3); each l_j sequential ascending; unfused mul/add.
// grid (64, 8): 128-token tile x 1024-code split; 16 ct-steps of 64 codes.

#define MAC_PHASE(ACC)                                                        \
    do {                                                                      \
        {                                                                     \
            const float4 za = *(const float4*)&zs[0][tg8];                    \
            const float4 zc4 = *(const float4*)&zs[0][tg8 + 4];               \
            const float4 ev = *(const float4*)&es[0][cg4];                    \
            const float zr[8] = {za.x, za.y, za.z, za.w,                      \
                                 zc4.x, zc4.y, zc4.z, zc4.w};                 \
            const float er4[4] = {ev.x, ev.y, ev.z, ev.w};                    \
            _Pragma("unroll") for (int i = 0; i < 8; ++i)                     \
                _Pragma("unroll") for (int jj = 0; jj < 4; ++jj)              \
                    ACC[i][jj] = zr[i] * er4[jj];                             \
        }                                                                     \
        _Pragma("unroll 3") for (int c = 1; c < 64; ++c) {                    \
            const float4 za = *(const float4*)&zs[c][tg8];                    \
            const float4 zc4 = *(const float4*)&zs[c][tg8 + 4];               \
            const float4 ev = *(const float4*)&es[c][cg4];                    \
            const float zr[8] = {za.x, za.y, za.z, za.w,                      \
                                 zc4.x, zc4.y, zc4.z, zc4.w};                 \
            const float er4[4] = {ev.x, ev.y, ev.z, ev.w};                    \
            _Pragma("unroll") for (int i = 0; i < 8; ++i)                     \
                _Pragma("unroll") for (int jj = 0; jj < 4; ++jj) {            \
                    const float p = zr[i] * er4[jj];                          \
                    ACC[i][jj] = ACC[i][jj] + p;                              \
                }                                                             \
        }                                                                     \
    } while (0)

#define STAGE_Z(R)                                                            \
    {                                                                         \
        const int j4 = (t & 31) * 4;                                          \
        const int c0 = t >> 5;                                                \
        _Pragma("unroll") for (int i = 0; i < 8; ++i) {                       \
            const int ci = c0 + i * 8;                                        \
            const float4 v =                                                  \
                *(const float4*)(zb + (size_t)(R + 4 * ci) * 1024 + j4);      \
            *(float4*)&zs[ci][j4] = v;                                        \
        }                                                                     \
    }

#define STAGE_E(R, K0)                                                        \
    {                                                                         \
        const int k = t & 63;                                                 \
        const int iq = t >> 6;                                                \
        const float* er = emb + (size_t)((K0) + k) * CDIM + (R) + iq * 64;    \
        _Pragma("unroll") for (int m = 0; m < 16; ++m) {                      \
            es[iq * 16 + m][k] = er[m * 4];                                   \
        }                                                                     \
    }

__global__ __launch_bounds__(256, 2) void vq_argmin_kernel(
        const float* __restrict__ z, const float* __restrict__ emb,
        const float* __restrict__ A, unsigned long long* __restrict__ pairs) {
    #pragma clang fp contract(off)
    extern __shared__ char smem[];
    float (*zs)[128] = (float (*)[128])smem;                          // [64][128] 32KB
    float (*es)[64]  = (float (*)[64])(smem + 32768);                 // [64][64]  16KB
    unsigned long long (*red)[16] = (unsigned long long (*)[16])smem; // alias zs

    const int t  = threadIdx.x;
    const int tg = t & 15;          // token group: tokens tg*8 .. tg*8+7
    const int cg = t >> 4;          // code group:  codes  cg*4 .. cg*4+3
    const int tg8 = tg * 8;
    const int cg4 = cg * 4;
    const int tile_t0 = blockIdx.x * 128;
    const int b   = tile_t0 >> 10;
    const int hw0 = tile_t0 & 1023;
    const int ks  = blockIdx.y * 1024;
    const float* zb = z + (size_t)b * (CDIM * 1024) + hw0;

    float Ar[8];
    #pragma unroll
    for (int i = 0; i < 8; ++i) Ar[i] = A[tile_t0 + tg8 + i];

    unsigned long long best[8];
    #pragma unroll
    for (int i = 0; i < 8; ++i) best[i] = ~0ull;

    for (int ct = 0; ct < 16; ++ct) {
        const int k0 = ks + ct * 64;
        float aL0[8][4], aL1[8][4], aL2[8][4];

        // ---- r = 0 -> aL0 (= l0) ----
        __syncthreads();
        STAGE_Z(0); STAGE_E(0, k0);
        __syncthreads();
        MAC_PHASE(aL0);

        // ---- r = 1 -> aL1 (= l1); p01 = l0 + l1 in place ----
        __syncthreads();
        STAGE_Z(1); STAGE_E(1, k0);
        __syncthreads();
        MAC_PHASE(aL1);
        #pragma unroll
        for (int i = 0; i < 8; ++i)
            #pragma unroll
            for (int jj = 0; jj < 4; ++jj) aL0[i][jj] = aL0[i][jj] + aL1[i][jj];

        // ---- r = 2 -> aL1 (= l2) ----
        __syncthreads();
        STAGE_Z(2); STAGE_E(2, k0);
        __syncthreads();
        MAC_PHASE(aL1);

        // ---- r = 3 -> aL2 (= l3) ----
        __syncthreads();
        STAGE_Z(3); STAGE_E(3, k0);
        __syncthreads();
        MAC_PHASE(aL2);

        // ---- fold: G = p01 + (l2 + l3); d = fl(A - 2G); first-index min ----
        #pragma unroll
        for (int i = 0; i < 8; ++i) {
            #pragma unroll
            for (int jj = 0; jj < 4; ++jj) {
                const float s23 = aL1[i][jj] + aL2[i][jj];
                const float g   = aL0[i][jj] + s23;
                const float d   = Ar[i] - 2.0f * g;
                const unsigned long long key =
                    ((unsigned long long)enc_f(d) << 32) | (unsigned)(k0 + cg4 + jj);
                if (key < best[i]) best[i] = key;
            }
        }
    }

    // ---- block reduce across the 16 code-groups per token ----
    __syncthreads();
    #pragma unroll
    for (int i = 0; i < 8; ++i) red[tg8 + i][cg] = best[i];
    __syncthreads();
    if (t < 128) {
        unsigned long long m = red[t][0];
        #pragma unroll
        for (int q = 1; q < 16; ++q) {
            const unsigned long long r = red[t][q];
            m = (r < m) ? r : m;
        }
        pairs[(size_t)(tile_t0 + t) * 8 + blockIdx.y] = m;
    }
}

// ---------------- merge splits -> fidx, out2, counts ----------------
__global__ void vq_combine_kernel(const unsigned long long* __restrict__ pairs,
                                  float* __restrict__ out2, unsigned* __restrict__ fidx,
                                  unsigned* __restrict__ counts) {
    const int n = blockIdx.x * blockDim.x + threadIdx.x;
    unsigned long long bk = pairs[(size_t)n * 8];
    #pragma unroll
    for (int s = 1; s < 8; ++s) {
        const unsigned long long k = pairs[(size_t)n * 8 + s];
        bk = (k < bk) ? k : bk;
    }
    const unsigned idx = (unsigned)(bk & 0xFFFFFFFFull);
    fidx[n] = idx;
    out2[n] = (float)idx;
    atomicAdd(&counts[idx], 1u);
}

// ---------------- gather z_q, ST-exact out0, per-batch MSE ----------------
__global__ void vq_gather_kernel(const unsigned* __restrict__ fidx,
                                 const float* __restrict__ emb,
                                 const float* __restrict__ z,
                                 float* __restrict__ out0, float* __restrict__ bsum) {
    #pragma clang fp contract(off)
    __shared__ float tile[64][257];
    const int t    = threadIdx.x;
    const int tok0 = blockIdx.x * 64;
    const int b    = tok0 >> 10;
    const int hw0  = tok0 & 1023;

    const int tt = t >> 2;
    const int q  = t & 3;
    const int idx = (int)fidx[tok0 + tt];
    const float* er = emb + (size_t)idx * CDIM;
    #pragma unroll
    for (int i = 0; i < 16; ++i) {
        const int f = i * 4 + q;
        float4 v = *(const float4*)(er + f * 4);
        tile[tt][f * 4 + 0] = v.x;
        tile[tt][f * 4 + 1] = v.y;
        tile[tt][f * 4 + 2] = v.z;
        tile[tt][f * 4 + 3] = v.w;
    }
    __syncthreads();

    const int j  = t & 63;
    const int c0 = t >> 6;
    const size_t base = (size_t)b * (CDIM * 1024) + hw0 + j;
    float s = 0.0f;
    #pragma unroll 4
    for (int c = c0; c < CDIM; c += 4) {
        const float v  = tile[j][c];
        const float zv = z[base + (size_t)c * 1024];
        const float d  = v - zv;                  // fl(z_q - z)
        out0[base + (size_t)c * 1024] = zv + d;   // straight-through
        s += d * d;
    }
    #pragma unroll
    for (int o = 32; o > 0; o >>= 1) s += __shfl_down(s, o, 64);
    __shared__ float w4[4];
    if ((t & 63) == 0) w4[t >> 6] = s;
    __syncthreads();
    if (t == 0) atomicAdd(&bsum[b], w4[0] + w4[1] + w4[2] + w4[3]);
}

// ---------------- finalize ----------------
__global__ void vq_final_kernel(const unsigned* __restrict__ counts,
                                const float* __restrict__ bsum,
                                float* __restrict__ out1, float* __restrict__ out3,
                                float* __restrict__ out4, float* __restrict__ out5) {
    const int t = threadIdx.x;
    float s = 0.0f;
    for (int k = t; k < N_CODES; k += 256) {
        const float p = (float)counts[k] * (1.0f / 8192.0f);
        s += p * logf(p + 1e-10f);
    }
    #pragma unroll
    for (int o = 32; o > 0; o >>= 1) s += __shfl_down(s, o, 64);
    __shared__ float w4[4];
    if ((t & 63) == 0) w4[t >> 6] = s;
    __syncthreads();
    if (t == 0) {
        out5[0] = expf(-(w4[0] + w4[1] + w4[2] + w4[3]));
        float tot = 0.0f;
        #pragma unroll
        for (int b = 0; b < 8; ++b) {
            const float m = bsum[b] * (1.0f / 262144.0f);
            out1[b] = 1.25f * m;
            tot += m;
        }
        const float mean_mse = tot * 0.125f;
        out3[0] = mean_mse;
        out4[0] = 0.25f * mean_mse;
    }
}

extern "C" void kernel_launch(void* const* d_in, const int* in_sizes, int n_in,
                              void* d_out, int out_size, void* d_ws, size_t ws_size,
                              hipStream_t stream) {
    const float* z   = (const float*)d_in[0];
    const float* emb = (const float*)d_in[1];
    float* out = (float*)d_out;

    float* out0 = out;                 // z_q_st (NCHW), 2097152
    float* out1 = out + 2097152;       // loss [8]
    float* out2 = out + 2097160;       // idx as float [8192]
    float* out3 = out + 2105352;       // mean commit
    float* out4 = out + 2105353;       // beta * mean emb
    float* out5 = out + 2105354;       // perplexity

    char* ws = (char*)d_ws;
    unsigned long long* pairs = (unsigned long long*)(ws + 0);
    float*    A      = (float*)(ws + 524288);
    unsigned* fidx   = (unsigned*)(ws + 557056);
    unsigned* counts = (unsigned*)(ws + 589824);
    float*    bsum   = (float*)(ws + 622592);

    hipMemsetAsync(ws + 589824, 0, 32768 + 32, stream);  // counts + bsum

    vq_A_kernel<<<N_TOKS / 256, 256, 0, stream>>>(z, A);
    vq_argmin_kernel<<<dim3(64, 8), 256, 49152, stream>>>(z, emb, A, pairs);
    vq_combine_kernel<<<N_TOKS / 256, 256, 0, stream>>>(pairs, out2, fidx, counts);
    vq_gather_kernel<<<N_TOKS / 64, 256, 0, stream>>>(fidx, emb, z, out0, bsum);
    vq_final_kernel<<<1, 256, 0, stream>>>(counts, bsum, out1, out3, out4, out5);
}

// Round 5
// 869.311 us; speedup vs baseline: 1.0771x; 1.0771x over previous
//
#include <hip/hip_runtime.h>

#pragma clang fp contract(off)

#define CDIM 256
#define N_TOKS 8192
#define N_CODES 8192

// token index -> padded LDS offset: groups of 8 tokens at stride 12 floats
// (48B) so the 16 per-wave ds_read_b128 addresses spread 2-way (free) instead
// of 4-way at stride 32B. Keeps 16B alignment (12 % 4 == 0).
#define ZMAP(x) ((x) + (((x) >> 3) << 2))

// ---------------- ws layout (bytes) ----------------
// 0       pairs   u64[8192*8]   512KB   per (token,split) packed (enc(d),idx)
// 524288  A       f32[8192]     32KB    np-pairwise ||z||^2 per token
// 557056  fidx    u32[8192]     32KB
// 589824  counts  u32[8192]     32KB
// 622592  bsum    f32[8]        32B

__device__ __forceinline__ unsigned enc_f(float f) {
    unsigned u = __float_as_uint(f);
    return (u & 0x80000000u) ? ~u : (u | 0x80000000u);
}

// ---------------- A_n = np.sum(zf*zf, axis=1) with numpy pairwise order ----
__global__ void vq_A_kernel(const float* __restrict__ z, float* __restrict__ A) {
    #pragma clang fp contract(off)
    const int n = blockIdx.x * blockDim.x + threadIdx.x;
    const int b = n >> 10, hw = n & 1023;
    const float* zp = z + (size_t)b * (CDIM * 1024) + hw;
    float halves[2];
    #pragma unroll
    for (int h = 0; h < 2; ++h) {
        const int base = h * 128;
        float r[8];
        #pragma unroll
        for (int j = 0; j < 8; ++j) {
            const float v = zp[(size_t)(base + j) * 1024];
            r[j] = v * v;
        }
        for (int i = 8; i < 128; i += 8) {
            #pragma unroll
            for (int j = 0; j < 8; ++j) {
                const float v = zp[(size_t)(base + i + j) * 1024];
                const float x = v * v;
                r[j] = r[j] + x;
            }
        }
        halves[h] = ((r[0] + r[1]) + (r[2] + r[3])) + ((r[4] + r[5]) + (r[6] + r[7]));
    }
    A[n] = halves[0] + halves[1];
}

// ---------------- main argmin: d_k = fl(A - 2*G_k), np.einsum SSE order ----
// G_k = (l0+l1)+(l2+l3), lane j = sequential unfused sum over channels == j mod 4.
// grid (64, 8): 128-token tile x 1024-code split; 16 ct-steps of 64 codes.
// 256 threads; micro-tile 8 tokens x 4 codes with acc[4 lanes][8][4].
// Static 66KB LDS -> hard 2-blocks/CU ceiling -> compiler targets 2 waves/SIMD
// -> 256-VGPR budget -> the 128 live accumulators fit WITHOUT spilling.
__global__ __launch_bounds__(256, 2) void vq_argmin_kernel(
        const float* __restrict__ z, const float* __restrict__ emb,
        const float* __restrict__ A, unsigned long long* __restrict__ pairs) {
    #pragma clang fp contract(off)
    __shared__ float zs[64][192];   // [channel][ZMAP(token)]  48KB
    __shared__ float es[64][72];    // [channel][code]         18KB
    unsigned long long (*red)[16] = (unsigned long long (*)[16])&zs[0][0];  // 16KB alias

    const int t  = threadIdx.x;
    const int tg = t & 15;          // token group: tokens tg*8 .. tg*8+7
    const int cg = t >> 4;          // code group:  codes  cg*4 .. cg*4+3
    const int tg8 = tg * 8;
    const int tgp = ZMAP(tg8);      // = tg * 12
    const int cg4 = cg * 4;
    const int tile_t0 = blockIdx.x * 128;
    const int b   = tile_t0 >> 10;
    const int hw0 = tile_t0 & 1023;
    const int ks  = blockIdx.y * 1024;
    const float* zb = z + (size_t)b * (CDIM * 1024) + hw0;

    float Ar[8];
    #pragma unroll
    for (int i = 0; i < 8; ++i) Ar[i] = A[tile_t0 + tg8 + i];

    unsigned long long best[8];
    #pragma unroll
    for (int i = 0; i < 8; ++i) best[i] = ~0ull;

    for (int ct = 0; ct < 16; ++ct) {
        const int k0 = ks + ct * 64;
        float acc[4][8][4];
        #pragma unroll
        for (int j = 0; j < 4; ++j)
            #pragma unroll
            for (int i = 0; i < 8; ++i)
                #pragma unroll
                for (int jj = 0; jj < 4; ++jj) acc[j][i][jj] = 0.0f;

        for (int cc = 0; cc < 4; ++cc) {
            const int cbase = cc * 64;
            __syncthreads();
            // ---- stage zs[c][tok], c in [cbase, cbase+64), coalesced float4 ----
            {
                const int j4 = (t & 31) * 4;
                const int jp = ZMAP(j4);
                const int c0 = t >> 5;
                #pragma unroll
                for (int i = 0; i < 8; ++i) {
                    const int c = c0 + i * 8;
                    float4 v = *(const float4*)(zb + (size_t)(cbase + c) * 1024 + j4);
                    *(float4*)&zs[c][jp] = v;
                }
            }
            // ---- stage es[c][code], 64 codes, float4 per emb row ----
            {
                const int k  = t & 63;
                const int cq = t >> 6;   // 0..3 -> channels cq*16..+15
                const float* er = emb + (size_t)(k0 + k) * CDIM + cbase + cq * 16;
                #pragma unroll
                for (int i = 0; i < 4; ++i) {
                    float4 v = *(const float4*)(er + i * 4);
                    es[cq * 16 + i * 4 + 0][k] = v.x;
                    es[cq * 16 + i * 4 + 1][k] = v.y;
                    es[cq * 16 + i * 4 + 2][k] = v.z;
                    es[cq * 16 + i * 4 + 3][k] = v.w;
                }
            }
            __syncthreads();
            // ---- unfused 4-lane accumulation (np.einsum SSE order) ----
            #pragma unroll 4
            for (int m = 0; m < 16; ++m) {
                #pragma unroll
                for (int j = 0; j < 4; ++j) {
                    const int c = m * 4 + j;   // lane j gets channels == j mod 4, ascending
                    const float4 za = *(const float4*)&zs[c][tgp];
                    const float4 zc = *(const float4*)&zs[c][tgp + 4];
                    const float4 ev = *(const float4*)&es[c][cg4];
                    const float zr[8] = {za.x, za.y, za.z, za.w, zc.x, zc.y, zc.z, zc.w};
                    const float er4[4] = {ev.x, ev.y, ev.z, ev.w};
                    #pragma unroll
                    for (int i = 0; i < 8; ++i)
                        #pragma unroll
                        for (int jj = 0; jj < 4; ++jj) {
                            const float p = zr[i] * er4[jj];   // rne product
                            acc[j][i][jj] = acc[j][i][jj] + p; // rne add (no FMA)
                        }
                }
            }
        }
        // ---- fold: G = (l0+l1)+(l2+l3); d = fl(A - 2G); packed first-index min ----
        #pragma unroll
        for (int i = 0; i < 8; ++i) {
            #pragma unroll
            for (int jj = 0; jj < 4; ++jj) {
                const float g = (acc[0][i][jj] + acc[1][i][jj])
                              + (acc[2][i][jj] + acc[3][i][jj]);
                const float d = Ar[i] - 2.0f * g;
                const unsigned long long key =
                    ((unsigned long long)enc_f(d) << 32) | (unsigned)(k0 + cg4 + jj);
                if (key < best[i]) best[i] = key;
            }
        }
    }

    // ---- block reduce across the 16 code-groups per token ----
    __syncthreads();
    #pragma unroll
    for (int i = 0; i < 8; ++i) red[tg8 + i][cg] = best[i];
    __syncthreads();
    if (t < 128) {
        unsigned long long m = red[t][0];
        #pragma unroll
        for (int q = 1; q < 16; ++q) {
            const unsigned long long r = red[t][q];
            m = (r < m) ? r : m;
        }
        pairs[(size_t)(tile_t0 + t) * 8 + blockIdx.y] = m;
    }
}

// ---------------- merge splits -> fidx, out2, counts ----------------
__global__ void vq_combine_kernel(const unsigned long long* __restrict__ pairs,
                                  float* __restrict__ out2, unsigned* __restrict__ fidx,
                                  unsigned* __restrict__ counts) {
    const int n = blockIdx.x * blockDim.x + threadIdx.x;
    unsigned long long bk = pairs[(size_t)n * 8];
    #pragma unroll
    for (int s = 1; s < 8; ++s) {
        const unsigned long long k = pairs[(size_t)n * 8 + s];
        bk = (k < bk) ? k : bk;
    }
    const unsigned idx = (unsigned)(bk & 0xFFFFFFFFull);
    fidx[n] = idx;
    out2[n] = (float)idx;
    atomicAdd(&counts[idx], 1u);
}

// ---------------- gather z_q, ST-exact out0, per-batch MSE ----------------
__global__ void vq_gather_kernel(const unsigned* __restrict__ fidx,
                                 const float* __restrict__ emb,
                                 const float* __restrict__ z,
                                 float* __restrict__ out0, float* __restrict__ bsum) {
    #pragma clang fp contract(off)
    __shared__ float tile[64][257];
    const int t    = threadIdx.x;
    const int tok0 = blockIdx.x * 64;
    const int b    = tok0 >> 10;
    const int hw0  = tok0 & 1023;

    const int tt = t >> 2;
    const int q  = t & 3;
    const int idx = (int)fidx[tok0 + tt];
    const float* er = emb + (size_t)idx * CDIM;
    #pragma unroll
    for (int i = 0; i < 16; ++i) {
        const int f = i * 4 + q;
        float4 v = *(const float4*)(er + f * 4);
        tile[tt][f * 4 + 0] = v.x;
        tile[tt][f * 4 + 1] = v.y;
        tile[tt][f * 4 + 2] = v.z;
        tile[tt][f * 4 + 3] = v.w;
    }
    __syncthreads();

    const int j  = t & 63;
    const int c0 = t >> 6;
    const size_t base = (size_t)b * (CDIM * 1024) + hw0 + j;
    float s = 0.0f;
    #pragma unroll 4
    for (int c = c0; c < CDIM; c += 4) {
        const float v  = tile[j][c];
        const float zv = z[base + (size_t)c * 1024];
        const float d  = v - zv;                  // fl(z_q - z)
        out0[base + (size_t)c * 1024] = zv + d;   // straight-through
        s += d * d;
    }
    #pragma unroll
    for (int o = 32; o > 0; o >>= 1) s += __shfl_down(s, o, 64);
    __shared__ float w4[4];
    if ((t & 63) == 0) w4[t >> 6] = s;
    __syncthreads();
    if (t == 0) atomicAdd(&bsum[b], w4[0] + w4[1] + w4[2] + w4[3]);
}

// ---------------- finalize ----------------
__global__ void vq_final_kernel(const unsigned* __restrict__ counts,
                                const float* __restrict__ bsum,
                                float* __restrict__ out1, float* __restrict__ out3,
                                float* __restrict__ out4, float* __restrict__ out5) {
    const int t = threadIdx.x;
    float s = 0.0f;
    for (int k = t; k < N_CODES; k += 256) {
        const float p = (float)counts[k] * (1.0f / 8192.0f);
        s += p * logf(p + 1e-10f);
    }
    #pragma unroll
    for (int o = 32; o > 0; o >>= 1) s += __shfl_down(s, o, 64);
    __shared__ float w4[4];
    if ((t & 63) == 0) w4[t >> 6] = s;
    __syncthreads();
    if (t == 0) {
        out5[0] = expf(-(w4[0] + w4[1] + w4[2] + w4[3]));
        float tot = 0.0f;
        #pragma unroll
        for (int b = 0; b < 8; ++b) {
            const float m = bsum[b] * (1.0f / 262144.0f);
            out1[b] = 1.25f * m;
            tot += m;
        }
        const float mean_mse = tot * 0.125f;
        out3[0] = mean_mse;
        out4[0] = 0.25f * mean_mse;
    }
}

extern "C" void kernel_launch(void* const* d_in, const int* in_sizes, int n_in,
                              void* d_out, int out_size, void* d_ws, size_t ws_size,
                              hipStream_t stream) {
    const float* z   = (const float*)d_in[0];
    const float* emb = (const float*)d_in[1];
    float* out = (float*)d_out;

    float* out0 = out;                 // z_q_st (NCHW), 2097152
    float* out1 = out + 2097152;       // loss [8]
    float* out2 = out + 2097160;       // idx as float [8192]
    float* out3 = out + 2105352;       // mean commit
    float* out4 = out + 2105353;       // beta * mean emb
    float* out5 = out + 2105354;       // perplexity

    char* ws = (char*)d_ws;
    unsigned long long* pairs = (unsigned long long*)(ws + 0);
    float*    A      = (float*)(ws + 524288);
    unsigned* fidx   = (unsigned*)(ws + 557056);
    unsigned* counts = (unsigned*)(ws + 589824);
    float*    bsum   = (float*)(ws + 622592);

    hipMemsetAsync(ws + 589824, 0, 32768 + 32, stream);  // counts + bsum

    vq_A_kernel<<<N_TOKS / 256, 256, 0, stream>>>(z, A);
    vq_argmin_kernel<<<dim3(64, 8), 256, 0, stream>>>(z, emb, A, pairs);
    vq_combine_kernel<<<N_TOKS / 256, 256, 0, stream>>>(pairs, out2, fidx, counts);
    vq_gather_kernel<<<N_TOKS / 64, 256, 0, stream>>>(fidx, emb, z, out0, bsum);
    vq_final_kernel<<<1, 256, 0, stream>>>(counts, bsum, out1, out3, out4, out5);
}